// Round 1
// baseline (181.024 us; speedup 1.0000x reference)
//
#include <hip/hip_runtime.h>
#include <math.h>

#define NB 4096
#define NS 50
#define NH 64
#define NITEM 40000

typedef float f4 __attribute__((ext_vector_type(4)));

// One kernel, two block roles:
//  - blocks [0, compute_blocks): 4 waves/block, one wave per batch row b.
//    Computes softmax(scores[b, :]) into probs[b*NS + s] (d_ws).
//  - blocks [compute_blocks, grid): grid-stride float4 non-temporal zeroing
//    of the 655 MB output. Independent of the compute half -> full overlap.
__global__ __launch_bounds__(256) void fused_zero_probs(
    const float* __restrict__ all_memory,   // [NB, NS, NH]
    const float* __restrict__ last_memory,  // [NB, NH]
    const float* __restrict__ Wr,           // [NH, NH]
    const float* __restrict__ Ur,           // [NH, NH]
    const float* __restrict__ Vr_w,         // [1, NH]
    const float* __restrict__ Vr_b,         // [1]
    float* __restrict__ out,                // [NB, NITEM]
    float* __restrict__ probs,              // [NB, NS] (workspace)
    int compute_blocks)
{
    const int bid = blockIdx.x;
    if (bid >= compute_blocks) {
        // ---------------- zero role ----------------
        const long long total4 = (long long)NB * NITEM / 4;  // divisible by 4
        f4* o4 = (f4*)out;
        long long idx = (long long)(bid - compute_blocks) * blockDim.x + threadIdx.x;
        const long long stride = (long long)(gridDim.x - compute_blocks) * blockDim.x;
        f4 z = (f4)(0.0f);
        for (long long i = idx; i < total4; i += stride)
            __builtin_nontemporal_store(z, o4 + i);
        return;
    }

    // ---------------- compute role: one wave per row b ----------------
    const int lane = threadIdx.x & 63;
    const int warp = __builtin_amdgcn_readfirstlane((int)(threadIdx.x >> 6));
    const int b = bid * 4 + warp;  // wave-uniform (SGPR)

    // Lane i owns output-dim i: keep Ur[i, :] in 64 VGPRs.
    float ur[NH];
    {
        const float* urow = Ur + lane * NH;
        #pragma unroll
        for (int h = 0; h < NH; h += 4) {
            float4 u = *(const float4*)(urow + h);
            ur[h] = u.x; ur[h + 1] = u.y; ur[h + 2] = u.z; ur[h + 3] = u.w;
        }
    }

    // lm[b, i] = dot(last_memory[b, :], Wr[i, :])  (computed once)
    float lm = 0.f;
    {
        const float* lrow = last_memory + b * NH;  // uniform address
        const float* wrow = Wr + lane * NH;
        #pragma unroll
        for (int h = 0; h < NH; h += 4) {
            float4 w = *(const float4*)(wrow + h);
            float4 l = *(const float4*)(lrow + h);
            lm += w.x * l.x + w.y * l.y + w.z * l.z + w.w * l.w;
        }
    }

    const float vw = Vr_w[lane];
    const float vb = Vr_b[0];
    const float* am = all_memory + (long long)b * (NS * NH);  // uniform base

    // scores: lane s ends up holding score[b, s]
    float myscore = 0.f;
    for (int s = 0; s < NS; ++s) {
        const float* arow = am + s * NH;  // wave-uniform -> scalar loads
        float v0 = 0.f, v1 = 0.f, v2 = 0.f, v3 = 0.f;
        #pragma unroll
        for (int h = 0; h < NH; h += 4) {
            float4 a = *(const float4*)(arow + h);
            v0 += a.x * ur[h];
            v1 += a.y * ur[h + 1];
            v2 += a.z * ur[h + 2];
            v3 += a.w * ur[h + 3];
        }
        float t = tanhf(lm + ((v0 + v1) + (v2 + v3))) * vw;
        // wave-wide sum over i (all 64 lanes)
        #pragma unroll
        for (int off = 32; off >= 1; off >>= 1)
            t += __shfl_xor(t, off, 64);
        t += vb;
        myscore = (lane == s) ? t : myscore;
    }

    // softmax over lanes 0..NS-1
    float sc = (lane < NS) ? myscore : -INFINITY;
    float m = sc;
    #pragma unroll
    for (int off = 32; off >= 1; off >>= 1)
        m = fmaxf(m, __shfl_xor(m, off, 64));
    float e = (lane < NS) ? expf(sc - m) : 0.f;
    float d = e;
    #pragma unroll
    for (int off = 32; off >= 1; off >>= 1)
        d += __shfl_xor(d, off, 64);
    if (lane < NS)
        probs[b * NS + lane] = e / d;
}

// One thread per (b, s): scatter prob onto the zeroed vocab row.
// atomicAdd accumulates duplicate items exactly like .at[].add.
__global__ __launch_bounds__(256) void scatter_k(
    const float* __restrict__ probs,
    const int* __restrict__ seq,
    float* __restrict__ out)
{
    int t = blockIdx.x * 256 + threadIdx.x;
    if (t >= NB * NS) return;
    int b = t / NS;
    float p = probs[t];
    int item = seq[t];
    atomicAdd(out + (long long)b * NITEM + item, p);
}

extern "C" void kernel_launch(void* const* d_in, const int* in_sizes, int n_in,
                              void* d_out, int out_size, void* d_ws, size_t ws_size,
                              hipStream_t stream) {
    const float* all_memory  = (const float*)d_in[0];
    const float* last_memory = (const float*)d_in[1];
    const float* Wr          = (const float*)d_in[2];
    const float* Ur          = (const float*)d_in[3];
    const float* Vr_w        = (const float*)d_in[4];
    const float* Vr_b        = (const float*)d_in[5];
    const int*   seq         = (const int*)d_in[6];
    float* out   = (float*)d_out;
    float* probs = (float*)d_ws;  // NB*NS floats = 819,200 B

    const int compute_blocks = NB / 4;          // 1024 (4 waves/block, 1 row/wave)
    const int zero_blocks    = 1024;
    fused_zero_probs<<<compute_blocks + zero_blocks, 256, 0, stream>>>(
        all_memory, last_memory, Wr, Ur, Vr_w, Vr_b, out, probs, compute_blocks);

    scatter_k<<<(NB * NS + 255) / 256, 256, 0, stream>>>(probs, seq, out);
}